// Round 6
// baseline (522.629 us; speedup 1.0000x reference)
//
#include <hip/hip_runtime.h>
#include <cstddef>

// Problem constants (fixed by setup_inputs)
static constexpr int Wd  = 256;   // sequence length (width)
static constexpr int NBd = 128;   // batch = hn*bs
static constexpr int Cd  = 128;   // channels
static constexpr int BSd = 2;     // bs
static constexpr int HNd = 64;    // hn
static constexpr size_t SEQF = (size_t)Wd * NBd * Cd;  // 4,194,304 elements

typedef __attribute__((ext_vector_type(8))) short bf16x8;
typedef __attribute__((ext_vector_type(4))) short bf16x4;
typedef __attribute__((ext_vector_type(2))) short bf16x2;
typedef __attribute__((ext_vector_type(4))) float f32x4;

__device__ inline short f2bf(float f) {
  union { float f; unsigned u; } v; v.f = f;
  return (short)((v.u + 0x7FFFu + ((v.u >> 16) & 1u)) >> 16);
}

// ---------------- to_seq: feat (bs,c,hn,w) -> seq (w, n=h*bs+b, c) fp32 ----------------
__global__ __launch_bounds__(256) void k_to_seq(const float* __restrict__ feat,
                                                float* __restrict__ out) {
  __shared__ float tile[32][33];
  int wi0 = blockIdx.x * 32, ci0 = blockIdx.y * 32;
  int hb = blockIdx.z;
  int h = hb >> 1, b = hb & 1;
  int tx = threadIdx.x, ty = threadIdx.y;
#pragma unroll
  for (int r = 0; r < 4; ++r) {
    int ci = ci0 + ty + r * 8;
    tile[ty + r * 8][tx] = feat[(((size_t)b * Cd + ci) * HNd + h) * Wd + wi0 + tx];
  }
  __syncthreads();
  int n = h * BSd + b;
#pragma unroll
  for (int r = 0; r < 4; ++r) {
    int wi = wi0 + ty + r * 8;
    out[((size_t)wi * NBd + n) * Cd + ci0 + tx] = tile[tx][ty + r * 8];
  }
}

// ---------------- from_seq: merged for both tensors ----------------
__global__ __launch_bounds__(256) void k_from_seq2(const float* __restrict__ seqA,
                                                   const float* __restrict__ seqB,
                                                   float* __restrict__ featA,
                                                   float* __restrict__ featB) {
  __shared__ float tile[32][33];
  int wi0 = blockIdx.x * 32, ci0 = blockIdx.y * 32;
  int z = blockIdx.z;
  const float* seq = (z < 128) ? seqA : seqB;
  float* feat = (z < 128) ? featA : featB;
  int hb = z & 127;
  int h = hb >> 1, b = hb & 1;
  int n = h * BSd + b;
  int tx = threadIdx.x, ty = threadIdx.y;
#pragma unroll
  for (int r = 0; r < 4; ++r) {
    int wi = wi0 + ty + r * 8;
    tile[ty + r * 8][tx] = seq[((size_t)wi * NBd + n) * Cd + ci0 + tx];
  }
  __syncthreads();
#pragma unroll
  for (int r = 0; r < 4; ++r) {
    int ci = ci0 + ty + r * 8;
    feat[(((size_t)b * Cd + ci) * HNd + h) * Wd + wi0 + tx] = tile[tx][ty + r * 8];
  }
}

// ---------------- LayerNorm: 8 rows per 512-thr block, wave per row ----------------
__global__ __launch_bounds__(512) void k_ln(const float* __restrict__ in,
                                            short* __restrict__ out,
                                            const float* __restrict__ g,
                                            const float* __restrict__ bb) {
  int wv = threadIdx.x >> 6, lane = threadIdx.x & 63;
  int row = blockIdx.x * 8 + wv;
  const float2 x2 = *(const float2*)&in[(size_t)row * Cd + lane * 2];
  float s1 = x2.x + x2.y, s2 = x2.x * x2.x + x2.y * x2.y;
#pragma unroll
  for (int m = 1; m < 64; m <<= 1) {
    s1 += __shfl_xor(s1, m);
    s2 += __shfl_xor(s2, m);
  }
  float mean = s1 * (1.0f / Cd);
  float var  = s2 * (1.0f / Cd) - mean * mean;
  float r = rsqrtf(var + 1e-5f);
  const float2 g2 = *(const float2*)&g[lane * 2];
  const float2 b2 = *(const float2*)&bb[lane * 2];
  bf16x2 o;
  o[0] = f2bf((x2.x - mean) * r * g2.x + b2.x);
  o[1] = f2bf((x2.y - mean) * r * g2.y + b2.y);
  *(bf16x2*)&out[(size_t)row * Cd + lane * 2] = o;
}

// ---------------- one-shot fp32->bf16 weight/pos convert ----------------
__global__ __launch_bounds__(256) void k_cvt(const float* __restrict__ w1, short* d1,  // 49152
                                             const float* __restrict__ w2, short* d2,  // 16384
                                             const float* __restrict__ w3, short* d3)  // 65408
{
  int i = blockIdx.x * 256 + threadIdx.x;
  if (i < 49152) d1[i] = f2bf(w1[i]);
  if (i < 16384) d2[i] = f2bf(w2[i]);
  if (i < 65408) d3[i] = f2bf(w3[i]);
}

// ---------------- bf16 MFMA GEMM, K=128, no LDS, no barriers ----------------
__global__ __launch_bounds__(256) void k_gemm_bf(
    const short* __restrict__ A, const short* __restrict__ Wt,
    const float* __restrict__ bias, const float* __restrict__ res,
    float* __restrict__ outF, short* __restrict__ outB,
    int M, int ldout, int scaleN0, float scale,
    const short* __restrict__ A2, short* __restrict__ outB2, int ldout2, int yCut) {
  const int t = threadIdx.x;
  const int lane = t & 63, wv = t >> 6;
  const int ml = lane & 15, quad = lane >> 4;
  const int m0 = blockIdx.x * 64;
  int yb = blockIdx.y;
  const short* Ap = A;
  short* oB = outB;
  float* oF = outF;
  const float* rs = res;
  int ld = ldout;
  int nblk = yb;
  if (yb >= yCut) { Ap = A2; oB = outB2; oF = nullptr; rs = nullptr; ld = ldout2; nblk = 0; }
  const int n0 = nblk * 128 + wv * 32;
  const bf16x8 zero8 = {0, 0, 0, 0, 0, 0, 0, 0};

  bf16x8 Bfr[2][4];
#pragma unroll
  for (int nf = 0; nf < 2; ++nf)
#pragma unroll
    for (int ks = 0; ks < 4; ++ks)
      Bfr[nf][ks] = *(const bf16x8*)&Wt[(size_t)(n0 + nf * 16 + ml) * 128 + ks * 32 + quad * 8];

  f32x4 acc[4][2];
#pragma unroll
  for (int mf = 0; mf < 4; ++mf)
#pragma unroll
    for (int nf = 0; nf < 2; ++nf) acc[mf][nf] = {0.f, 0.f, 0.f, 0.f};

#pragma unroll
  for (int ks = 0; ks < 4; ++ks) {
    bf16x8 Af[4];
#pragma unroll
    for (int mf = 0; mf < 4; ++mf) {
      int m = m0 + mf * 16 + ml;
      Af[mf] = (m < M) ? *(const bf16x8*)&Ap[(size_t)m * 128 + ks * 32 + quad * 8] : zero8;
    }
#pragma unroll
    for (int mf = 0; mf < 4; ++mf)
#pragma unroll
      for (int nf = 0; nf < 2; ++nf)
        acc[mf][nf] = __builtin_amdgcn_mfma_f32_16x16x32_bf16(Af[mf], Bfr[nf][ks], acc[mf][nf], 0, 0, 0);
  }

#pragma unroll
  for (int nf = 0; nf < 2; ++nf) {
    int n = n0 + nf * 16 + ml;
    float bi = bias[n];
    float sc = (n < scaleN0) ? scale : 1.0f;
#pragma unroll
    for (int mf = 0; mf < 4; ++mf) {
#pragma unroll
      for (int r = 0; r < 4; ++r) {
        int m = m0 + mf * 16 + quad * 4 + r;
        if (m >= M) continue;
        float v = (acc[mf][nf][r] + bi) * sc;
        if (rs) v += rs[(size_t)m * ld + n];
        if (oF) oF[(size_t)m * ld + n] = v;
        if (oB) oB[(size_t)m * ld + n] = f2bf(v);
      }
    }
  }
}

// ---------------- MFMA fused attention, head-split (bf16 in / bf16 out) ----------------
// Grid (4 i-panels, 128 n, 8 heads). One head per block -> LDS ~38 KB, 4 blocks/CU.
// K/V^T staged in LDS (reused by all 4 waves); Q / PQ / PK windows read directly
// from global (PP is 256 KB, L2-resident). 2 barriers per block, none in jt loop.
// PASS==2: p = i-j+255. PASS==1: p = j-i+255 (flipped pos).
template <int PASS>
__global__ __launch_bounds__(256, 4) void k_attn_mfma(
    const short* __restrict__ Qg, int ldq,
    const short* __restrict__ Kg, const short* __restrict__ Vg, int ldkv,
    const short* __restrict__ PP, short* __restrict__ O) {
  __shared__ short Ks[256][16];
  __shared__ short VTs[16][264];
  __shared__ float R2s[4][16][34];
  __shared__ float R3s[4][16][34];
  __shared__ short Ps[4][16][40];

  const int t = threadIdx.x;
  const int n = blockIdx.y;
  const int e = blockIdx.z;
  const int i0p = blockIdx.x * 64;
  const int lane = t & 63, wv = t >> 6;
  const int ml = lane & 15, quad = lane >> 4;
  const bool lo = lane < 32;
  const int wb = (PASS == 2) ? i0p : (192 - i0p);
  const bf16x8 zero8 = {0, 0, 0, 0, 0, 0, 0, 0};
  const f32x4 z4 = {0.f, 0.f, 0.f, 0.f};

#pragma unroll
  for (int it = 0; it < 4; ++it) {  // K rows: 256 rows x 4 chunks of 4 shorts
    int idx = t + it * 256;
    int r = idx >> 2, c4 = idx & 3;
    *(bf16x4*)&Ks[r][c4 * 4] =
        *(const bf16x4*)&Kg[((size_t)r * NBd + n) * ldkv + e * 16 + c4 * 4];
  }
#pragma unroll
  for (int it = 0; it < 4; ++it) {  // V transposed: row-linear lanes
    bf16x4 vv = *(const bf16x4*)&Vg[((size_t)t * NBd + n) * ldkv + e * 16 + it * 4];
    VTs[it * 4 + 0][t] = vv[0];
    VTs[it * 4 + 1][t] = vv[1];
    VTs[it * 4 + 2][t] = vv[2];
    VTs[it * 4 + 3][t] = vv[3];
  }
  __syncthreads();

  bf16x8 bQ = lo ? *(const bf16x8*)&Qg[((size_t)(i0p + 16 * wv + ml) * NBd + n) * ldq +
                                       e * 16 + quad * 8]
                 : zero8;
  f32x4 Ot = {0.f, 0.f, 0.f, 0.f};
  float den = 0.f;
#pragma unroll
  for (int jt = 0; jt < 16; ++jt) {
    const int j0 = jt * 16;
    bf16x8 aK = lo ? *(const bf16x8*)&Ks[j0 + ml][quad * 8] : zero8;
    const int pb = (PASS == 2) ? (16 * wv - j0 + 240) : (j0 - 16 * wv + 48);
    int p0 = wb + pb + ml;
    int p1 = p0 + 16;
    if (p0 > 510) p0 = 510;
    if (p1 > 510) p1 = 510;
    const short* pr0 = &PP[(size_t)p0 * 256 + e * 16];
    const short* pr1 = &PP[(size_t)p1 * 256 + e * 16];
    bf16x8 bPK0 = lo ? *(const bf16x8*)&pr0[128 + quad * 8] : zero8;
    bf16x8 bPK1 = lo ? *(const bf16x8*)&pr1[128 + quad * 8] : zero8;
    bf16x8 bPQ0 = lo ? *(const bf16x8*)&pr0[quad * 8] : zero8;
    bf16x8 bPQ1 = lo ? *(const bf16x8*)&pr1[quad * 8] : zero8;

    f32x4 St  = __builtin_amdgcn_mfma_f32_16x16x32_bf16(aK, bQ, z4, 0, 0, 0);
    f32x4 R2a = __builtin_amdgcn_mfma_f32_16x16x32_bf16(bQ, bPK0, z4, 0, 0, 0);
    f32x4 R2b = __builtin_amdgcn_mfma_f32_16x16x32_bf16(bQ, bPK1, z4, 0, 0, 0);
    f32x4 R3a = __builtin_amdgcn_mfma_f32_16x16x32_bf16(aK, bPQ0, z4, 0, 0, 0);
    f32x4 R3b = __builtin_amdgcn_mfma_f32_16x16x32_bf16(aK, bPQ1, z4, 0, 0, 0);
#pragma unroll
    for (int r = 0; r < 4; ++r) {
      R2s[wv][quad * 4 + r][ml]      = R2a[r];
      R2s[wv][quad * 4 + r][ml + 16] = R2b[r];
      R3s[wv][quad * 4 + r][ml]      = R3a[r];
      R3s[wv][quad * 4 + r][ml + 16] = R3b[r];
    }
#pragma unroll
    for (int r = 0; r < 4; ++r) {
      const int jl = quad * 4 + r;
      const int pcol = (PASS == 2) ? (ml - jl + 15) : (jl - ml + 15);
      float s = St[r] + R2s[wv][ml][pcol] + R3s[wv][jl][pcol];
      float pe = __expf(s);
      den += pe;
      Ps[wv][ml][(jt & 1) * 16 + jl] = f2bf(pe);
    }
    if (jt & 1) {
      bf16x8 aVT = *(const bf16x8*)&VTs[ml][(jt >> 1) * 32 + quad * 8];
      bf16x8 bP  = *(const bf16x8*)&Ps[wv][ml][quad * 8];
      Ot = __builtin_amdgcn_mfma_f32_16x16x32_bf16(aVT, bP, Ot, 0, 0, 0);
    }
  }
  den += __shfl_xor(den, 16);
  den += __shfl_xor(den, 32);
  float inv = 1.f / den;
  bf16x4 ob;
  ob[0] = f2bf(Ot[0] * inv); ob[1] = f2bf(Ot[1] * inv);
  ob[2] = f2bf(Ot[2] * inv); ob[3] = f2bf(Ot[3] * inv);
  *(bf16x4*)&O[((size_t)(i0p + 16 * wv + ml) * NBd + n) * Cd + e * 16 + quad * 4] = ob;
}

// ---------------- raw = sum_e pre-softmax scores, computed dense with K=128 ----------------
// raw[n,i,j] = Qf[i,n]·Kf[j,n] + Qf[i,n]·PKf[p] + Kf[j,n]·PQf[p], p=i-j+255 (pass 2).
// S-form MFMA (row=i, col=j) -> coalesced row-major writes. Per-wave LDS gathers only,
// zero barriers. Grid (4 i-panels, 128 n, 4 j-quarters).
__global__ __launch_bounds__(256, 4) void k_raw(
    const short* __restrict__ Qf, const short* __restrict__ Kf,
    const short* __restrict__ PP, float* __restrict__ raw) {
  __shared__ float R2s[4][16][34];
  __shared__ float R3s[4][16][34];
  const int t = threadIdx.x;
  const int n = blockIdx.y;
  const int lane = t & 63, wv = t >> 6;
  const int ml = lane & 15, quad = lane >> 4;
  const int it0 = blockIdx.x * 64 + wv * 16;
  const int jt0 = blockIdx.z * 4;
  const f32x4 z4 = {0.f, 0.f, 0.f, 0.f};

  bf16x8 aQ[4];
#pragma unroll
  for (int kc = 0; kc < 4; ++kc)
    aQ[kc] = *(const bf16x8*)&Qf[((size_t)(it0 + ml) * NBd + n) * 384 + kc * 32 + quad * 8];

  float* rbase = &raw[(((size_t)(n & 1) * HNd + (n >> 1)) * Wd + it0) * Wd];

#pragma unroll
  for (int jq = 0; jq < 4; ++jq) {
    const int j0 = (jt0 + jq) * 16;
    bf16x8 aK[4];
#pragma unroll
    for (int kc = 0; kc < 4; ++kc)
      aK[kc] = *(const bf16x8*)&Kf[((size_t)(j0 + ml) * NBd + n) * 256 + kc * 32 + quad * 8];
    f32x4 St = z4, R2a = z4, R2b = z4, R3a = z4, R3b = z4;
#pragma unroll
    for (int kc = 0; kc < 4; ++kc)
      St = __builtin_amdgcn_mfma_f32_16x16x32_bf16(aQ[kc], aK[kc], St, 0, 0, 0);
    int p0 = it0 - j0 + 240 + ml;
    int p1 = p0 + 16;
    if (p1 > 510) p1 = 510;  // p0 <= 240+240+15 = 495 always in range; row 511 never gathered
    const short* pr0 = &PP[(size_t)p0 * 256];
    const short* pr1 = &PP[(size_t)p1 * 256];
#pragma unroll
    for (int kc = 0; kc < 4; ++kc) {
      bf16x8 b0 = *(const bf16x8*)&pr0[128 + kc * 32 + quad * 8];
      R2a = __builtin_amdgcn_mfma_f32_16x16x32_bf16(aQ[kc], b0, R2a, 0, 0, 0);
    }
#pragma unroll
    for (int kc = 0; kc < 4; ++kc) {
      bf16x8 b1 = *(const bf16x8*)&pr1[128 + kc * 32 + quad * 8];
      R2b = __builtin_amdgcn_mfma_f32_16x16x32_bf16(aQ[kc], b1, R2b, 0, 0, 0);
    }
#pragma unroll
    for (int kc = 0; kc < 4; ++kc) {
      bf16x8 b0 = *(const bf16x8*)&pr0[kc * 32 + quad * 8];
      R3a = __builtin_amdgcn_mfma_f32_16x16x32_bf16(aK[kc], b0, R3a, 0, 0, 0);
    }
#pragma unroll
    for (int kc = 0; kc < 4; ++kc) {
      bf16x8 b1 = *(const bf16x8*)&pr1[kc * 32 + quad * 8];
      R3b = __builtin_amdgcn_mfma_f32_16x16x32_bf16(aK[kc], b1, R3b, 0, 0, 0);
    }
#pragma unroll
    for (int r = 0; r < 4; ++r) {
      R2s[wv][quad * 4 + r][ml]      = R2a[r];
      R2s[wv][quad * 4 + r][ml + 16] = R2b[r];
      R3s[wv][quad * 4 + r][ml]      = R3a[r];
      R3s[wv][quad * 4 + r][ml + 16] = R3b[r];
    }
#pragma unroll
    for (int r = 0; r < 4; ++r) {
      const int il = quad * 4 + r;
      const int pcol = il - ml + 15;
      rbase[(size_t)il * Wd + j0 + ml] = St[r] + R2s[wv][il][pcol] + R3s[wv][ml][pcol];
    }
  }
}

extern "C" void kernel_launch(void* const* d_in, const int* in_sizes, int n_in,
                              void* d_out, int out_size, void* d_ws, size_t ws_size,
                              hipStream_t stream) {
  const float* feat_l = (const float*)d_in[0];
  const float* feat_r = (const float*)d_in[1];
  const float* pos    = (const float*)d_in[2];
  // d_in[3] = pos_indexes (int) -- structure known analytically, unused.
  const float* Wqkv = (const float*)d_in[4];
  const float* bqkv = (const float*)d_in[5];
  const float* Wo   = (const float*)d_in[6];
  const float* bo   = (const float*)d_in[7];
  const float* g1   = (const float*)d_in[8];
  const float* b1   = (const float*)d_in[9];
  const float* g2   = (const float*)d_in[10];
  const float* b2   = (const float*)d_in[11];
  float* out = (float*)d_out;

  float* ws = (float*)d_ws;
  float* fl_seq = ws;                 // fp32
  float* fr_seq = ws + SEQF;          // fp32
  float* fr2_f  = ws + 2 * SEQF;      // fp32 (fr_new)
  float* fl_new = ws + 3 * SEQF;      // fp32
  short* wsb    = (short*)(ws + 4 * SEQF);
  short* fl2_b   = wsb;               // SEQF bf16
  short* fr2_b   = wsb + SEQF;
  short* frb2_b  = wsb + 2 * SEQF;
  short* QKVl_b  = wsb + 3 * SEQF;    // 3*SEQF
  short* Qr_b    = wsb + 6 * SEQF;
  short* KVr2_b  = wsb + 7 * SEQF;    // 2*SEQF
  short* O_b     = wsb + 9 * SEQF;
  short* PP_b    = wsb + 10 * SEQF;   // 511*256
  short* Wb      = PP_b + 131072;     // Wqkv (49152) then Wo (16384)
  short* pos_b   = Wb + 65536;        // 511*128

  dim3 tgrid(8, 4, 128), tblk(32, 8);
  k_to_seq<<<tgrid, tblk, 0, stream>>>(feat_l, fl_seq);
  k_to_seq<<<tgrid, tblk, 0, stream>>>(feat_r, fr_seq);
  k_cvt<<<256, 256, 0, stream>>>(Wqkv, Wb, Wo, Wb + 49152, pos, pos_b);
  k_ln<<<4096, 512, 0, stream>>>(fl_seq, fl2_b, g1, b1);
  k_ln<<<4096, 512, 0, stream>>>(fr_seq, fr2_b, g1, b1);

  // PP = [PQ(scaled)|PK] projections of the 511 pos rows (bf16 out)
  k_gemm_bf<<<dim3(8, 2), 256, 0, stream>>>(pos_b, Wb, bqkv, nullptr, nullptr, PP_b,
                                            511, 256, 128, 0.25f,
                                            nullptr, nullptr, 0, 999);
  // QKV of fl2 (Q scaled) + Q of fr2 (scaled), merged
  k_gemm_bf<<<dim3(512, 4), 256, 0, stream>>>(fl2_b, Wb, bqkv, nullptr, nullptr, QKVl_b,
                                              32768, 384, 128, 0.25f,
                                              fr2_b, Qr_b, 128, 3);

  // mha1: q=fr2-proj, kv=fl2-proj, flipped pos => p = j-i+255
  k_attn_mfma<1><<<dim3(4, 128, 8), 256, 0, stream>>>(
      Qr_b, Cd, QKVl_b + 128, QKVl_b + 256, 384, PP_b, O_b);
  // fr_new = fr_seq + O @ Wo^T + bo (fp32 out)
  k_gemm_bf<<<dim3(512, 1), 256, 0, stream>>>(O_b, Wb + 49152, bo, fr_seq, fr2_f, nullptr,
                                              32768, 128, 0, 1.0f,
                                              nullptr, nullptr, 0, 999);
  // frb2 = ln(fr_new, g2, b2) (bf16)
  k_ln<<<4096, 512, 0, stream>>>(fr2_f, frb2_b, g2, b2);
  // KV of frb2
  k_gemm_bf<<<dim3(512, 2), 256, 0, stream>>>(frb2_b, Wb + 16384, bqkv + 128, nullptr,
                                              nullptr, KVr2_b, 32768, 256, 0, 1.0f,
                                              nullptr, nullptr, 0, 999);
  // mha2: q=fl2-proj (in QKVl), kv=frb2-proj; p = i-j+255
  k_attn_mfma<2><<<dim3(4, 128, 8), 256, 0, stream>>>(
      QKVl_b, 384, KVr2_b, KVr2_b + 128, 256, PP_b, O_b);
  // raw = sum over heads of pre-softmax scores (dense K=128 formulation)
  k_raw<<<dim3(4, 128, 4), 256, 0, stream>>>(QKVl_b, KVr2_b, PP_b, out + 2 * SEQF);
  // fl_new = fl_seq + O @ Wo^T + bo
  k_gemm_bf<<<dim3(512, 1), 256, 0, stream>>>(O_b, Wb + 49152, bo, fl_seq, fl_new, nullptr,
                                              32768, 128, 0, 1.0f,
                                              nullptr, nullptr, 0, 999);

  k_from_seq2<<<dim3(8, 4, 256), tblk, 0, stream>>>(fl_new, fr2_f, out, out + SEQF);

  (void)in_sizes; (void)n_in; (void)out_size; (void)ws_size;
}

// Round 7
// 429.180 us; speedup vs baseline: 1.2177x; 1.2177x over previous
//
#include <hip/hip_runtime.h>
#include <cstddef>

// Problem constants (fixed by setup_inputs)
static constexpr int Wd  = 256;   // sequence length (width)
static constexpr int NBd = 128;   // batch = hn*bs
static constexpr int Cd  = 128;   // channels
static constexpr int BSd = 2;     // bs
static constexpr int HNd = 64;    // hn
static constexpr size_t SEQF = (size_t)Wd * NBd * Cd;  // 4,194,304 elements

typedef __attribute__((ext_vector_type(8))) short bf16x8;
typedef __attribute__((ext_vector_type(4))) short bf16x4;
typedef __attribute__((ext_vector_type(4))) float f32x4;

__device__ inline short f2bf(float f) {
  union { float f; unsigned u; } v; v.f = f;
  return (short)((v.u + 0x7FFFu + ((v.u >> 16) & 1u)) >> 16);
}

// ---------------- fused to_seq + LayerNorm ----------------
// feat (bs,c,hn,w) -> seq fp32 (w,n,c) AND ln(seq) bf16. grid (8 wtiles, 256 z).
__global__ __launch_bounds__(256) void k_to_seq_ln(
    const float* __restrict__ fA, const float* __restrict__ fB,
    float* __restrict__ seqA, float* __restrict__ seqB,
    short* __restrict__ lnA, short* __restrict__ lnB,
    const float* __restrict__ g, const float* __restrict__ bb) {
  __shared__ float red[2][8][33];
  __shared__ float mv[2][32];
  const int z = blockIdx.y;
  const float* feat = (z < 128) ? fA : fB;
  float* seq = (z < 128) ? seqA : seqB;
  short* lno = (z < 128) ? lnA : lnB;
  const int hb = z & 127;
  const int h = hb >> 1, b = hb & 1;
  const int n = h * BSd + b;
  const int w0 = blockIdx.x * 32;
  const int t = threadIdx.x;
  const int wl = t & 31, cg = t >> 5, c0 = cg * 16;
  float v[16];
  float s1 = 0.f, s2 = 0.f;
#pragma unroll
  for (int r = 0; r < 16; ++r) {
    v[r] = feat[(((size_t)b * Cd + c0 + r) * HNd + h) * Wd + w0 + wl];
    s1 += v[r]; s2 += v[r] * v[r];
  }
  red[0][cg][wl] = s1; red[1][cg][wl] = s2;
  __syncthreads();
  if (t < 32) {
    float a1 = 0.f, a2 = 0.f;
#pragma unroll
    for (int k = 0; k < 8; ++k) { a1 += red[0][k][t]; a2 += red[1][k][t]; }
    float mean = a1 * (1.0f / Cd);
    float var = a2 * (1.0f / Cd) - mean * mean;
    mv[0][t] = mean; mv[1][t] = rsqrtf(var + 1e-5f);
  }
  __syncthreads();
  const float mean = mv[0][wl], rstd = mv[1][wl];
  float* so = &seq[((size_t)(w0 + wl) * NBd + n) * Cd + c0];
  short* bo_ = &lno[((size_t)(w0 + wl) * NBd + n) * Cd + c0];
#pragma unroll
  for (int r = 0; r < 16; ++r) so[r] = v[r];
#pragma unroll
  for (int r = 0; r < 16; ++r)
    bo_[r] = f2bf((v[r] - mean) * rstd * g[c0 + r] + bb[c0 + r]);
}

// ---------------- from_seq: merged for both tensors ----------------
__global__ __launch_bounds__(256) void k_from_seq2(const float* __restrict__ seqA,
                                                   const float* __restrict__ seqB,
                                                   float* __restrict__ featA,
                                                   float* __restrict__ featB) {
  __shared__ float tile[32][33];
  int wi0 = blockIdx.x * 32, ci0 = blockIdx.y * 32;
  int z = blockIdx.z;
  const float* seq = (z < 128) ? seqA : seqB;
  float* feat = (z < 128) ? featA : featB;
  int hb = z & 127;
  int h = hb >> 1, b = hb & 1;
  int n = h * BSd + b;
  int tx = threadIdx.x, ty = threadIdx.y;
#pragma unroll
  for (int r = 0; r < 4; ++r) {
    int wi = wi0 + ty + r * 8;
    tile[ty + r * 8][tx] = seq[((size_t)wi * NBd + n) * Cd + ci0 + tx];
  }
  __syncthreads();
#pragma unroll
  for (int r = 0; r < 4; ++r) {
    int ci = ci0 + ty + r * 8;
    feat[(((size_t)b * Cd + ci) * HNd + h) * Wd + wi0 + tx] = tile[tx][ty + r * 8];
  }
}

// ---------------- one-shot fp32->bf16 weight/pos convert ----------------
__global__ __launch_bounds__(256) void k_cvt(const float* __restrict__ w1, short* d1,  // 49152
                                             const float* __restrict__ w2, short* d2,  // 16384
                                             const float* __restrict__ w3, short* d3)  // 65408
{
  int i = blockIdx.x * 256 + threadIdx.x;
  if (i < 49152) d1[i] = f2bf(w1[i]);
  if (i < 16384) d2[i] = f2bf(w2[i]);
  if (i < 65408) d3[i] = f2bf(w3[i]);
}

// ---------------- bf16 MFMA GEMM, K=128, no LDS, no barriers ----------------
__global__ __launch_bounds__(256) void k_gemm_bf(
    const short* __restrict__ A, const short* __restrict__ Wt,
    const float* __restrict__ bias, float* __restrict__ outF,
    short* __restrict__ outB, int M, int ldout, int scaleN0, float scale,
    const short* __restrict__ A2, short* __restrict__ outB2, int ldout2, int yCut) {
  const int t = threadIdx.x;
  const int lane = t & 63, wv = t >> 6;
  const int ml = lane & 15, quad = lane >> 4;
  const int m0 = blockIdx.x * 64;
  int yb = blockIdx.y;
  const short* Ap = A;
  short* oB = outB;
  float* oF = outF;
  int ld = ldout;
  int nblk = yb;
  if (yb >= yCut) { Ap = A2; oB = outB2; oF = nullptr; ld = ldout2; nblk = 0; }
  const int n0 = nblk * 128 + wv * 32;
  const bf16x8 zero8 = {0, 0, 0, 0, 0, 0, 0, 0};

  bf16x8 Bfr[2][4];
#pragma unroll
  for (int nf = 0; nf < 2; ++nf)
#pragma unroll
    for (int ks = 0; ks < 4; ++ks)
      Bfr[nf][ks] = *(const bf16x8*)&Wt[(size_t)(n0 + nf * 16 + ml) * 128 + ks * 32 + quad * 8];

  f32x4 acc[4][2];
#pragma unroll
  for (int mf = 0; mf < 4; ++mf)
#pragma unroll
    for (int nf = 0; nf < 2; ++nf) acc[mf][nf] = {0.f, 0.f, 0.f, 0.f};

#pragma unroll
  for (int ks = 0; ks < 4; ++ks) {
    bf16x8 Af[4];
#pragma unroll
    for (int mf = 0; mf < 4; ++mf) {
      int m = m0 + mf * 16 + ml;
      Af[mf] = (m < M) ? *(const bf16x8*)&Ap[(size_t)m * 128 + ks * 32 + quad * 8] : zero8;
    }
#pragma unroll
    for (int mf = 0; mf < 4; ++mf)
#pragma unroll
      for (int nf = 0; nf < 2; ++nf)
        acc[mf][nf] = __builtin_amdgcn_mfma_f32_16x16x32_bf16(Af[mf], Bfr[nf][ks], acc[mf][nf], 0, 0, 0);
  }

#pragma unroll
  for (int nf = 0; nf < 2; ++nf) {
    int n = n0 + nf * 16 + ml;
    float bi = bias[n];
    float sc = (n < scaleN0) ? scale : 1.0f;
#pragma unroll
    for (int mf = 0; mf < 4; ++mf) {
#pragma unroll
      for (int r = 0; r < 4; ++r) {
        int m = m0 + mf * 16 + quad * 4 + r;
        if (m >= M) continue;
        float v = (acc[mf][nf][r] + bi) * sc;
        if (oF) oF[(size_t)m * ld + n] = v;
        if (oB) oB[(size_t)m * ld + n] = f2bf(v);
      }
    }
  }
}

// ---------------- Wo GEMM + residual + optional fused LayerNorm ----------------
// Wave handles 16 full rows (all 128 n-cols) -> LN stats via 16-lane shuffles, no LDS.
__global__ __launch_bounds__(256) void k_gemm_wo_ln(
    const short* __restrict__ A, const short* __restrict__ Wt,
    const float* __restrict__ bias, const float* __restrict__ res,
    float* __restrict__ outF, short* __restrict__ outLN,
    const float* __restrict__ lng, const float* __restrict__ lnb) {
  const int t = threadIdx.x;
  const int lane = t & 63, wv = t >> 6;
  const int ml = lane & 15, quad = lane >> 4;
  const int m0 = blockIdx.x * 64 + wv * 16;

  f32x4 acc[8];
#pragma unroll
  for (int nf = 0; nf < 8; ++nf) acc[nf] = {0.f, 0.f, 0.f, 0.f};
#pragma unroll
  for (int ks = 0; ks < 4; ++ks) {
    bf16x8 Af = *(const bf16x8*)&A[(size_t)(m0 + ml) * 128 + ks * 32 + quad * 8];
#pragma unroll
    for (int nf = 0; nf < 8; ++nf) {
      bf16x8 Bf = *(const bf16x8*)&Wt[(size_t)(nf * 16 + ml) * 128 + ks * 32 + quad * 8];
      acc[nf] = __builtin_amdgcn_mfma_f32_16x16x32_bf16(Af, Bf, acc[nf], 0, 0, 0);
    }
  }
  float val[8][4];
#pragma unroll
  for (int nf = 0; nf < 8; ++nf) {
    float bi = bias[nf * 16 + ml];
#pragma unroll
    for (int r = 0; r < 4; ++r) {
      int m = m0 + quad * 4 + r;
      val[nf][r] = acc[nf][r] + bi + res[(size_t)m * 128 + nf * 16 + ml];
      outF[(size_t)m * 128 + nf * 16 + ml] = val[nf][r];
    }
  }
  if (outLN) {
#pragma unroll
    for (int r = 0; r < 4; ++r) {
      float s1 = 0.f, s2 = 0.f;
#pragma unroll
      for (int nf = 0; nf < 8; ++nf) { s1 += val[nf][r]; s2 += val[nf][r] * val[nf][r]; }
#pragma unroll
      for (int mk = 1; mk < 16; mk <<= 1) { s1 += __shfl_xor(s1, mk); s2 += __shfl_xor(s2, mk); }
      float mean = s1 * (1.0f / 128.f);
      float var = s2 * (1.0f / 128.f) - mean * mean;
      float rstd = rsqrtf(var + 1e-5f);
      int m = m0 + quad * 4 + r;
#pragma unroll
      for (int nf = 0; nf < 8; ++nf) {
        int nn = nf * 16 + ml;
        outLN[(size_t)m * 128 + nn] = f2bf((val[nf][r] - mean) * rstd * lng[nn] + lnb[nn]);
      }
    }
  }
}

// ---------------- MFMA fused attention, head-split + i-panel loop ----------------
// Grid (n=128, e=8). K/V^T staged once, reused across 4 i-panels. Banded-pos reuse:
// R2 second half = previous tile's first-half MFMA RESULT (bQ loop-invariant) via
// 2-bank LDS rotation; PQ fragment reused (saves load; aK varies so R3 recomputed).
// PASS==2: p = i-j+255. PASS==1: p = j-i+255 (flipped pos).
template <int PASS>
__global__ __launch_bounds__(256, 4) void k_attn_mfma(
    const short* __restrict__ Qg, int ldq,
    const short* __restrict__ Kg, const short* __restrict__ Vg, int ldkv,
    const short* __restrict__ PP, short* __restrict__ O) {
  __shared__ short Ks[256][16];
  __shared__ short VTs[16][264];
  __shared__ float R2s[4][2][16][17];
  __shared__ float R3s[4][16][34];
  __shared__ short Ps[4][16][40];

  const int t = threadIdx.x;
  const int n = blockIdx.x;
  const int e = blockIdx.y;
  const int lane = t & 63, wv = t >> 6;
  const int ml = lane & 15, quad = lane >> 4;
  const bool lo = lane < 32;
  const bf16x8 zero8 = {0, 0, 0, 0, 0, 0, 0, 0};
  const f32x4 z4 = {0.f, 0.f, 0.f, 0.f};

#pragma unroll
  for (int it = 0; it < 4; ++it) {  // K rows: 256 rows x 4 chunks of 4 shorts
    int idx = t + it * 256;
    int r = idx >> 2, c4 = idx & 3;
    *(bf16x4*)&Ks[r][c4 * 4] =
        *(const bf16x4*)&Kg[((size_t)r * NBd + n) * ldkv + e * 16 + c4 * 4];
  }
#pragma unroll
  for (int it = 0; it < 4; ++it) {  // V transposed: row-linear lanes
    bf16x4 vv = *(const bf16x4*)&Vg[((size_t)t * NBd + n) * ldkv + e * 16 + it * 4];
    VTs[it * 4 + 0][t] = vv[0];
    VTs[it * 4 + 1][t] = vv[1];
    VTs[it * 4 + 2][t] = vv[2];
    VTs[it * 4 + 3][t] = vv[3];
  }
  __syncthreads();

  const short* PPe = PP + e * 16;

  for (int ip = 0; ip < 4; ++ip) {
    const int i0p = ip * 64;
    const int wb = (PASS == 2) ? i0p : (192 - i0p);
    bf16x8 bQ = lo ? *(const bf16x8*)&Qg[((size_t)(i0p + 16 * wv + ml) * NBd + n) * ldq +
                                         e * 16 + quad * 8]
                   : zero8;
    f32x4 Ot = {0.f, 0.f, 0.f, 0.f};
    float den = 0.f;

    // init prev half (bank 1)
    bf16x8 fPQprev;
    {
      int pp = (PASS == 2) ? (wb + 16 * wv + 256 + ml) : (wb - 16 * wv + 48 + ml);
      if (pp > 510) pp = 510;
      const short* pr = &PPe[(size_t)pp * 256];
      bf16x8 fPK = lo ? *(const bf16x8*)&pr[128 + quad * 8] : zero8;
      fPQprev    = lo ? *(const bf16x8*)&pr[quad * 8] : zero8;
      f32x4 R2i = __builtin_amdgcn_mfma_f32_16x16x32_bf16(bQ, fPK, z4, 0, 0, 0);
#pragma unroll
      for (int r = 0; r < 4; ++r) R2s[wv][1][quad * 4 + r][ml] = R2i[r];
    }

#pragma unroll
    for (int jt = 0; jt < 16; ++jt) {
      const int j0 = jt * 16;
      bf16x8 aK = lo ? *(const bf16x8*)&Ks[j0 + ml][quad * 8] : zero8;
      int pf = (PASS == 2) ? (wb + 16 * wv - j0 + 240 + ml)
                           : (wb - 16 * wv + j0 + 64 + ml);
      if (pf > 510) pf = 510;
      const short* prf = &PPe[(size_t)pf * 256];
      bf16x8 fPK  = lo ? *(const bf16x8*)&prf[128 + quad * 8] : zero8;
      bf16x8 fPQf = lo ? *(const bf16x8*)&prf[quad * 8] : zero8;

      f32x4 St  = __builtin_amdgcn_mfma_f32_16x16x32_bf16(aK, bQ, z4, 0, 0, 0);
      f32x4 R2f = __builtin_amdgcn_mfma_f32_16x16x32_bf16(bQ, fPK, z4, 0, 0, 0);
      f32x4 R3a, R3b;
      if (PASS == 2) {
        R3a = __builtin_amdgcn_mfma_f32_16x16x32_bf16(aK, fPQf, z4, 0, 0, 0);
        R3b = __builtin_amdgcn_mfma_f32_16x16x32_bf16(aK, fPQprev, z4, 0, 0, 0);
      } else {
        R3b = __builtin_amdgcn_mfma_f32_16x16x32_bf16(aK, fPQf, z4, 0, 0, 0);
        R3a = __builtin_amdgcn_mfma_f32_16x16x32_bf16(aK, fPQprev, z4, 0, 0, 0);
      }
      fPQprev = fPQf;
#pragma unroll
      for (int r = 0; r < 4; ++r) {
        R2s[wv][jt & 1][quad * 4 + r][ml] = R2f[r];
        R3s[wv][quad * 4 + r][ml]       = R3a[r];
        R3s[wv][quad * 4 + r][ml + 16]  = R3b[r];
      }
#pragma unroll
      for (int r = 0; r < 4; ++r) {
        const int jl = quad * 4 + r;
        const int pcol = (PASS == 2) ? (ml - jl + 15) : (jl - ml + 15);
        const int hi = pcol >> 4, col = pcol & 15;
        const int bk = (jt & 1) ^ hi ^ (PASS == 1 ? 1 : 0);
        float s = St[r] + R2s[wv][bk][ml][col] + R3s[wv][jl][pcol];
        float pe = __expf(s);
        den += pe;
        Ps[wv][ml][(jt & 1) * 16 + jl] = f2bf(pe);
      }
      if (jt & 1) {
        bf16x8 aVT = *(const bf16x8*)&VTs[ml][(jt >> 1) * 32 + quad * 8];
        bf16x8 bP  = *(const bf16x8*)&Ps[wv][ml][quad * 8];
        Ot = __builtin_amdgcn_mfma_f32_16x16x32_bf16(aVT, bP, Ot, 0, 0, 0);
      }
    }
    den += __shfl_xor(den, 16);
    den += __shfl_xor(den, 32);
    float inv = 1.f / den;
    bf16x4 ob;
    ob[0] = f2bf(Ot[0] * inv); ob[1] = f2bf(Ot[1] * inv);
    ob[2] = f2bf(Ot[2] * inv); ob[3] = f2bf(Ot[3] * inv);
    *(bf16x4*)&O[((size_t)(i0p + 16 * wv + ml) * NBd + n) * Cd + e * 16 + quad * 4] = ob;
  }
}

// ---------------- raw = sum_e pre-softmax scores, dense K=128 ----------------
// Banded reuse: R2 second half = prev jq's first-half RESULT (aQ invariant);
// PQ fragments carried across jq (saves loads). Grid (4 i-panels, 128 n, 4 j-quarters).
__global__ __launch_bounds__(256, 4) void k_raw(
    const short* __restrict__ Qf, const short* __restrict__ Kf,
    const short* __restrict__ PP, float* __restrict__ raw) {
  __shared__ float R2s[4][2][16][17];
  __shared__ float R3s[4][16][34];
  const int t = threadIdx.x;
  const int n = blockIdx.y;
  const int lane = t & 63, wv = t >> 6;
  const int ml = lane & 15, quad = lane >> 4;
  const int it0 = blockIdx.x * 64 + wv * 16;
  const int jt0 = blockIdx.z * 4;
  const f32x4 z4 = {0.f, 0.f, 0.f, 0.f};

  bf16x8 aQ[4];
#pragma unroll
  for (int kc = 0; kc < 4; ++kc)
    aQ[kc] = *(const bf16x8*)&Qf[((size_t)(it0 + ml) * NBd + n) * 384 + kc * 32 + quad * 8];

  float* rbase = &raw[(((size_t)(n & 1) * HNd + (n >> 1)) * Wd + it0) * Wd];

  bf16x8 fPQprev[4];
  {
    int pp = it0 - jt0 * 16 + 256 + ml;
    if (pp > 510) pp = 510;
    const short* pr = &PP[(size_t)pp * 256];
    f32x4 R2i = z4;
#pragma unroll
    for (int kc = 0; kc < 4; ++kc) {
      bf16x8 fPK = *(const bf16x8*)&pr[128 + kc * 32 + quad * 8];
      R2i = __builtin_amdgcn_mfma_f32_16x16x32_bf16(aQ[kc], fPK, R2i, 0, 0, 0);
      fPQprev[kc] = *(const bf16x8*)&pr[kc * 32 + quad * 8];
    }
#pragma unroll
    for (int r = 0; r < 4; ++r) R2s[wv][1][quad * 4 + r][ml] = R2i[r];
  }

#pragma unroll
  for (int jq = 0; jq < 4; ++jq) {
    const int j0 = (jt0 + jq) * 16;
    bf16x8 aK[4];
#pragma unroll
    for (int kc = 0; kc < 4; ++kc)
      aK[kc] = *(const bf16x8*)&Kf[((size_t)(j0 + ml) * NBd + n) * 256 + kc * 32 + quad * 8];
    const int p0 = it0 - j0 + 240 + ml;  // in [0,495] always
    const short* pr0 = &PP[(size_t)p0 * 256];
    f32x4 St = z4, R2f = z4, R3a = z4, R3b = z4;
    bf16x8 fPQ0[4];
#pragma unroll
    for (int kc = 0; kc < 4; ++kc)
      St = __builtin_amdgcn_mfma_f32_16x16x32_bf16(aQ[kc], aK[kc], St, 0, 0, 0);
#pragma unroll
    for (int kc = 0; kc < 4; ++kc) {
      bf16x8 fPK0 = *(const bf16x8*)&pr0[128 + kc * 32 + quad * 8];
      R2f = __builtin_amdgcn_mfma_f32_16x16x32_bf16(aQ[kc], fPK0, R2f, 0, 0, 0);
    }
#pragma unroll
    for (int kc = 0; kc < 4; ++kc) {
      fPQ0[kc] = *(const bf16x8*)&pr0[kc * 32 + quad * 8];
      R3a = __builtin_amdgcn_mfma_f32_16x16x32_bf16(aK[kc], fPQ0[kc], R3a, 0, 0, 0);
    }
#pragma unroll
    for (int kc = 0; kc < 4; ++kc)
      R3b = __builtin_amdgcn_mfma_f32_16x16x32_bf16(aK[kc], fPQprev[kc], R3b, 0, 0, 0);
#pragma unroll
    for (int kc = 0; kc < 4; ++kc) fPQprev[kc] = fPQ0[kc];
#pragma unroll
    for (int r = 0; r < 4; ++r) {
      R2s[wv][jq & 1][quad * 4 + r][ml] = R2f[r];
      R3s[wv][quad * 4 + r][ml]      = R3a[r];
      R3s[wv][quad * 4 + r][ml + 16] = R3b[r];
    }
#pragma unroll
    for (int r = 0; r < 4; ++r) {
      const int il = quad * 4 + r;
      const int pcol = il - ml + 15;
      const int hi = pcol >> 4, col = pcol & 15;
      const int bk = (jq & 1) ^ hi;
      rbase[(size_t)il * Wd + j0 + ml] = St[r] + R2s[wv][bk][il][col] + R3s[wv][ml][pcol];
    }
  }
}

extern "C" void kernel_launch(void* const* d_in, const int* in_sizes, int n_in,
                              void* d_out, int out_size, void* d_ws, size_t ws_size,
                              hipStream_t stream) {
  const float* feat_l = (const float*)d_in[0];
  const float* feat_r = (const float*)d_in[1];
  const float* pos    = (const float*)d_in[2];
  // d_in[3] = pos_indexes (int) -- structure known analytically, unused.
  const float* Wqkv = (const float*)d_in[4];
  const float* bqkv = (const float*)d_in[5];
  const float* Wo   = (const float*)d_in[6];
  const float* bo   = (const float*)d_in[7];
  const float* g1   = (const float*)d_in[8];
  const float* b1   = (const float*)d_in[9];
  const float* g2   = (const float*)d_in[10];
  const float* b2   = (const float*)d_in[11];
  float* out = (float*)d_out;

  float* ws = (float*)d_ws;
  float* fl_seq = ws;                 // fp32
  float* fr_seq = ws + SEQF;          // fp32
  float* fr2_f  = ws + 2 * SEQF;      // fp32 (fr_new)
  float* fl_new = ws + 3 * SEQF;      // fp32
  short* wsb    = (short*)(ws + 4 * SEQF);
  short* fl2_b   = wsb;               // SEQF bf16
  short* fr2_b   = wsb + SEQF;
  short* frb2_b  = wsb + 2 * SEQF;
  short* QKVl_b  = wsb + 3 * SEQF;    // 3*SEQF
  short* Qr_b    = wsb + 6 * SEQF;
  short* KVr2_b  = wsb + 7 * SEQF;    // 2*SEQF
  short* O_b     = wsb + 9 * SEQF;
  short* PP_b    = wsb + 10 * SEQF;   // 511*256
  short* Wb      = PP_b + 131072;     // Wqkv (49152) then Wo (16384)
  short* pos_b   = Wb + 65536;        // 511*128

  // to_seq + LN(g1,b1) fused, both tensors
  k_to_seq_ln<<<dim3(8, 256), 256, 0, stream>>>(feat_l, feat_r, fl_seq, fr_seq,
                                                fl2_b, fr2_b, g1, b1);
  k_cvt<<<256, 256, 0, stream>>>(Wqkv, Wb, Wo, Wb + 49152, pos, pos_b);

  // PP = [PQ(scaled)|PK] projections of the 511 pos rows (bf16 out)
  k_gemm_bf<<<dim3(8, 2), 256, 0, stream>>>(pos_b, Wb, bqkv, nullptr, PP_b,
                                            511, 256, 128, 0.25f,
                                            nullptr, nullptr, 0, 999);
  // QKV of fl2 (Q scaled) + Q of fr2 (scaled), merged
  k_gemm_bf<<<dim3(512, 4), 256, 0, stream>>>(fl2_b, Wb, bqkv, nullptr, QKVl_b,
                                              32768, 384, 128, 0.25f,
                                              fr2_b, Qr_b, 128, 3);

  // mha1: q=fr2-proj, kv=fl2-proj, flipped pos => p = j-i+255
  k_attn_mfma<1><<<dim3(128, 8), 256, 0, stream>>>(
      Qr_b, Cd, QKVl_b + 128, QKVl_b + 256, 384, PP_b, O_b);
  // fr_new = fr_seq + O @ Wo^T + bo  (+ fused LN(g2,b2) -> frb2_b)
  k_gemm_wo_ln<<<512, 256, 0, stream>>>(O_b, Wb + 49152, bo, fr_seq, fr2_f,
                                        frb2_b, g2, b2);
  // KV of frb2
  k_gemm_bf<<<dim3(512, 2), 256, 0, stream>>>(frb2_b, Wb + 16384, bqkv + 128, nullptr,
                                              KVr2_b, 32768, 256, 0, 1.0f,
                                              nullptr, nullptr, 0, 999);
  // mha2: q=fl2-proj (in QKVl), kv=frb2-proj; p = i-j+255
  k_attn_mfma<2><<<dim3(128, 8), 256, 0, stream>>>(
      QKVl_b, 384, KVr2_b, KVr2_b + 128, 256, PP_b, O_b);
  // raw = sum over heads of pre-softmax scores (dense K=128 formulation)
  k_raw<<<dim3(4, 128, 4), 256, 0, stream>>>(QKVl_b, KVr2_b, PP_b, out + 2 * SEQF);
  // fl_new = fl_seq + O @ Wo^T + bo (no LN)
  k_gemm_wo_ln<<<512, 256, 0, stream>>>(O_b, Wb + 49152, bo, fl_seq, fl_new,
                                        nullptr, nullptr, nullptr);

  k_from_seq2<<<dim3(8, 4, 256), dim3(32, 8), 0, stream>>>(fl_new, fr2_f, out, out + SEQF);

  (void)in_sizes; (void)n_in; (void)out_size; (void)ws_size;
}